// Round 2
// baseline (309.276 us; speedup 1.0000x reference)
//
#include <hip/hip_runtime.h>

// Problem constants (from reference): SEQ=1024, B=32, H=1024
#define SEQ 1024
#define NCH 32768  // B*H independent channels
#define UNR 16     // timesteps prefetched per register buffer

// One thread per channel. Layout is [t][channel] with channel fastest, so
// lane i reads channel base+i -> fully coalesced at every timestep.
// The recurrence serializes over t within a thread, but all load addresses
// are independent of the FMA chain, so we double-buffer UNR steps of (f,x)
// in registers: while chunk c's chain computes, chunk c+1's loads are in
// flight. 2 buffers x 16 steps x 2 arrays = 64 VGPRs of data; ~8KB
// outstanding per wave, 2 waves/CU -> enough MLP to hide ~900cyc HBM latency.
__global__ __launch_bounds__(64) void fm_scan(const float* __restrict__ f,
                                              const float* __restrict__ x,
                                              const float* __restrict__ h0,
                                              float* __restrict__ out) {
    const int idx = blockIdx.x * 64 + threadIdx.x;  // channel id
    const float* fp = f + idx;
    const float* xp = x + idx;
    float* op = out + idx;

    float h = h0[idx];

    float fA[UNR], xA[UNR], fB[UNR], xB[UNR];

    // Prefetch chunk 0 into A.
#pragma unroll
    for (int j = 0; j < UNR; ++j) {
        fA[j] = fp[j * NCH];
        xA[j] = xp[j * NCH];
    }

    constexpr int NC = SEQ / UNR;  // 64 chunks, processed 2 per iteration
    for (int c = 0; c < NC; c += 2) {
        // Chunk c starts at TIMESTEP c*UNR -> element offset c*UNR*NCH.
        // (Round-1 bug: was c*NCH, i.e. timestep c — wrote wrong rows.)
        const size_t base = (size_t)c * UNR * NCH;

        // Prefetch odd chunk (c+1) into B — issues before A's FMA chain.
#pragma unroll
        for (int j = 0; j < UNR; ++j) {
            fB[j] = fp[base + (size_t)(UNR + j) * NCH];
            xB[j] = xp[base + (size_t)(UNR + j) * NCH];
        }

        // Compute even chunk from A. h = f*x + (1-f)*h == h + f*(x-h)
#pragma unroll
        for (int j = 0; j < UNR; ++j) {
            h = fmaf(fA[j], xA[j] - h, h);
            op[base + (size_t)j * NCH] = h;
        }

        // Prefetch next even chunk (c+2) into A.
        if (c + 2 < NC) {
#pragma unroll
            for (int j = 0; j < UNR; ++j) {
                fA[j] = fp[base + (size_t)(2 * UNR + j) * NCH];
                xA[j] = xp[base + (size_t)(2 * UNR + j) * NCH];
            }
        }

        // Compute odd chunk from B.
#pragma unroll
        for (int j = 0; j < UNR; ++j) {
            h = fmaf(fB[j], xB[j] - h, h);
            op[base + (size_t)(UNR + j) * NCH] = h;
        }
    }
}

extern "C" void kernel_launch(void* const* d_in, const int* in_sizes, int n_in,
                              void* d_out, int out_size, void* d_ws, size_t ws_size,
                              hipStream_t stream) {
    const float* f  = (const float*)d_in[0];
    const float* x  = (const float*)d_in[1];
    const float* h0 = (const float*)d_in[2];
    float* out = (float*)d_out;

    // 512 blocks of 64 threads: 2 blocks/CU over all 256 CUs.
    fm_scan<<<dim3(NCH / 64), dim3(64), 0, stream>>>(f, x, h0, out);
}